// Round 7
// baseline (994.040 us; speedup 1.0000x reference)
//
#include <hip/hip_runtime.h>

#define Vn 128
#define En 32
#define Hn 128
#define Bn 4
#define Sn 512
#define G4H 512   // 4*Hn

typedef _Float16 half8 __attribute__((ext_vector_type(8)));
typedef _Float16 half4v __attribute__((ext_vector_type(4)));
typedef float    floatx4 __attribute__((ext_vector_type(4)));

__device__ __forceinline__ float fsigmoid(float x) {
    return 1.0f / (1.0f + __expf(-x));
}

__device__ __forceinline__ float ftanh(float x) {
    float ax = fabsf(x);
    float e  = __expf(2.0f * ax);
    float t  = 1.0f - 2.0f / (e + 1.0f);
    return copysignf(t, x);
}

// ---------------------------------------------------------------------------
// Kernel A': Gtab[v][g] = (b_ih+b_hh)[g] + sum_e emb[v][e] * W_ih[g][e]
// ---------------------------------------------------------------------------
__global__ __launch_bounds__(512) void k_gtab(
        const float* __restrict__ emb, const float* __restrict__ Wih,
        const float* __restrict__ bih, const float* __restrict__ bhh,
        float* __restrict__ Gtab) {
    int v = blockIdx.x;
    int g = threadIdx.x;
    __shared__ float e[En];
    if (g < En) e[g] = emb[v * En + g];
    __syncthreads();
    const float4* wr = (const float4*)(Wih + g * En);
    float acc = bih[g] + bhh[g];
#pragma unroll
    for (int i = 0; i < En / 4; i++) {
        float4 w4 = wr[i];
        acc += w4.x * e[4*i] + w4.y * e[4*i+1] + w4.z * e[4*i+2] + w4.w * e[4*i+3];
    }
    Gtab[v * G4H + g] = acc;
}

// ---------------------------------------------------------------------------
// Kernel B (R11): MFMA LSTM, gate-interleaved tiles, ONE barrier/step.
// One block, 512 threads. Wave wv owns j in [16wv, 16wv+16) for ALL 4 gates:
// A-tile g covers W rows g*128 + 16wv + (0..15). Lane (cn = l&15 = batch/
// A-row, kg = l>>4): D frag d[g] holds rows j = 16wv + kg*4 + reg, col = cn.
// => each lane has gi/gf/gg/go for ITS four j-rows in registers: the LSTM
// activation needs NO LDS round-trip, NO second barrier, NO separate phase
// (R10's 2-barrier gbuf pipeline was the 2093-cyc/step cost).
// x-path Gtab float4s are prefetched one step ahead (token-dependent only),
// so d += gx never waits on VMEM. h -> fp16 -> double-buffered hbuf; write
// then ONE barrier; next step's B-frag reads it. hbuf stride 144 halves:
// b128 reads worst 2-way (free, m136), h-writes 16 distinct banks.
// A-fragments (64 regs/lane) loaded+cvt'd once; MFMA reads them natively
// from AGPRs (R10-proven: no shuttle tax).
// ---------------------------------------------------------------------------
__global__ __attribute__((amdgpu_flat_work_group_size(512, 512),
                          amdgpu_waves_per_eu(2, 2)))
void k_lstm(
        const float* __restrict__ Whh, const float* __restrict__ Gtab,
        const int* __restrict__ x,
        float* __restrict__ out, float* __restrict__ hT, float* __restrict__ cT) {
    int tid = threadIdx.x;
    int wv  = tid >> 6;    // wave 0..7: owns j-range [16wv, 16wv+16)
    int l   = tid & 63;
    int cn  = l & 15;      // MFMA A-row within tile / D col (batch if < 4)
    int kg  = l >> 4;      // k-group 0..3
    int cb  = cn & 3;      // clamped batch (lanes cn>=4 duplicate, masked off)
    int j0  = 16 * wv + kg * 4;   // first of this lane's 4 j-rows

    __shared__ int xb[4][520];                       // padded: bank-spread
    __shared__ alignas(16) _Float16 hbuf[2][4][144]; // h fp16, double-buffered

    for (int i = tid; i < Bn * Sn; i += 512) xb[i >> 9][i & 511] = x[i];
    for (int i = tid; i < 2 * 4 * 144; i += 512) ((_Float16*)hbuf)[i] = (_Float16)0.0f;

    // ---- A-fragments: af[gate][kc], loaded + converted ONCE ----
    half8 af[4][4];
#pragma unroll
    for (int g = 0; g < 4; g++) {
#pragma unroll
        for (int kc = 0; kc < 4; kc++) {
            int row = g * Hn + 16 * wv + cn;
            int kb  = kc * 32 + kg * 8;
            const float4* p = (const float4*)(Whh + row * Hn + kb);
            float4 lo = p[0], hi = p[1];
            half8 a = { (_Float16)lo.x, (_Float16)lo.y, (_Float16)lo.z, (_Float16)lo.w,
                        (_Float16)hi.x, (_Float16)hi.y, (_Float16)hi.z, (_Float16)hi.w };
            af[g][kc] = a;
        }
    }

    float c0 = 0.f, c1 = 0.f, c2 = 0.f, c3 = 0.f;
    float h0 = 0.f, h1 = 0.f, h2 = 0.f, h3 = 0.f;
    __syncthreads();

    // prefetch step-0 x-path preactivations (gate g, rows j0..j0+3)
    floatx4 gx[4];
    {
        const float* gp = Gtab + xb[cb][0] * G4H + j0;
#pragma unroll
        for (int g = 0; g < 4; g++) gx[g] = *(const floatx4*)(gp + g * Hn);
    }

    int cur = 0;
    for (int s = 0; s < Sn; s++) {
        // B-fragments from hbuf[cur]: col = batch, k = kc*32+kg*8+(0..7)
        half8 bf[4];
#pragma unroll
        for (int kc = 0; kc < 4; kc++)
            bf[kc] = *(const half8*)&hbuf[cur][cb][kc * 32 + kg * 8];

        // 16 MFMAs: 4 gates x 4 K-chunks, fp32 accumulate
        floatx4 d[4];
#pragma unroll
        for (int g = 0; g < 4; g++) {
            floatx4 acc = { 0.f, 0.f, 0.f, 0.f };
#pragma unroll
            for (int kc = 0; kc < 4; kc++)
                acc = __builtin_amdgcn_mfma_f32_16x16x32_f16(af[g][kc], bf[kc], acc, 0, 0, 0);
            d[g] = acc + gx[g];   // fold x-path (bias included)
        }

        // prefetch NEXT step's gx (token-only dependence: hides L2 latency)
        {
            int sn = (s + 1 < Sn) ? s + 1 : s;
            const float* gp = Gtab + xb[cb][sn] * G4H + j0;
#pragma unroll
            for (int g = 0; g < 4; g++) gx[g] = *(const floatx4*)(gp + g * Hn);
        }

        // in-register activation: 4 independent rows (ILP-4)
        c0 = fsigmoid(d[1][0]) * c0 + fsigmoid(d[0][0]) * ftanh(d[2][0]);
        c1 = fsigmoid(d[1][1]) * c1 + fsigmoid(d[0][1]) * ftanh(d[2][1]);
        c2 = fsigmoid(d[1][2]) * c2 + fsigmoid(d[0][2]) * ftanh(d[2][2]);
        c3 = fsigmoid(d[1][3]) * c3 + fsigmoid(d[0][3]) * ftanh(d[2][3]);
        h0 = fsigmoid(d[3][0]) * ftanh(c0);
        h1 = fsigmoid(d[3][1]) * ftanh(c1);
        h2 = fsigmoid(d[3][2]) * ftanh(c2);
        h3 = fsigmoid(d[3][3]) * ftanh(c3);

        if (cn < 4) {
            float4 hv = { h0, h1, h2, h3 };
            *(float4*)(out + cb * Sn * Hn + s * Hn + j0) = hv;
            half4v hp = { (_Float16)h0, (_Float16)h1, (_Float16)h2, (_Float16)h3 };
            *(half4v*)&hbuf[cur ^ 1][cb][j0] = hp;
        }
        __syncthreads();   // h(s) published; next step reads hbuf[cur^1]
        cur ^= 1;
    }
    if (cn < 4) {
        float4 hv = { h0, h1, h2, h3 };
        float4 cv = { c0, c1, c2, c3 };
        *(float4*)(hT + cb * Hn + j0) = hv;
        *(float4*)(cT + cb * Hn + j0) = cv;
    }
}

// ---------------------------------------------------------------------------
// Kernel C: q = out@Wq.T + bq ; k = out@Wk.T + bk
// ---------------------------------------------------------------------------
__global__ __launch_bounds__(256) void k_qk(
        const float* __restrict__ out, const float* __restrict__ Wq,
        const float* __restrict__ bq, const float* __restrict__ Wk,
        const float* __restrict__ bk, float* __restrict__ qo, float* __restrict__ ko) {
    int bs  = blockIdx.x;
    int tid = threadIdx.x;
    __shared__ float o[Hn];
    if (tid < Hn) o[tid] = out[bs * Hn + tid];
    __syncthreads();
    int h = tid & 127;
    const float* Wm = (tid < Hn) ? Wq : Wk;
    const float* bm = (tid < Hn) ? bq : bk;
    const float4* wr = (const float4*)(Wm + h * Hn);
    float acc = bm[h];
#pragma unroll
    for (int i = 0; i < Hn / 4; i++) {
        float4 w4 = wr[i];
        acc += w4.x * o[4*i] + w4.y * o[4*i+1] + w4.z * o[4*i+2] + w4.w * o[4*i+3];
    }
    float* dst = (tid < Hn) ? qo : ko;
    dst[bs * Hn + h] = acc;
}

// ---------------------------------------------------------------------------
// Kernel D: Bahdanau scores + causal softmax + ctx. Block per (b,t).
// ---------------------------------------------------------------------------
__global__ __launch_bounds__(512) void k_attn(
        const float* __restrict__ qo, const float* __restrict__ ko,
        const float* __restrict__ vvec, const float* __restrict__ out,
        float* __restrict__ ctx) {
    int b   = blockIdx.x >> 9;
    int t   = blockIdx.x & (Sn - 1);
    int tid = threadIdx.x;
    __shared__ float qs[Hn];
    __shared__ float vs[Hn];
    __shared__ float sc[Sn];
    __shared__ float red[512];
    __shared__ float part[16][Hn];

    if (tid < Hn) {
        qs[tid] = qo[(b * Sn + t) * Hn + tid];
        vs[tid] = vvec[tid];
    }
    __syncthreads();

    float a = -1e30f;
    if (tid <= t) {
        const float4* kr = (const float4*)(ko + (b * Sn + tid) * Hn);
        float s = 0.0f;
#pragma unroll
        for (int u = 0; u < Hn / 4; u++) {
            float4 k4 = kr[u];
            s += vs[4*u]   * ftanh(qs[4*u]   + k4.x);
            s += vs[4*u+1] * ftanh(qs[4*u+1] + k4.y);
            s += vs[4*u+2] * ftanh(qs[4*u+2] + k4.z);
            s += vs[4*u+3] * ftanh(qs[4*u+3] + k4.w);
        }
        sc[tid] = s;
        a = s;
    }
    red[tid] = a;
    __syncthreads();
    for (int off = 256; off > 0; off >>= 1) {
        if (tid < off) red[tid] = fmaxf(red[tid], red[tid + off]);
        __syncthreads();
    }
    float m = red[0];
    __syncthreads();

    float ev = 0.0f;
    if (tid <= t) {
        ev = __expf(sc[tid] - m);
        sc[tid] = ev;
    }
    red[tid] = ev;
    __syncthreads();
    for (int off = 256; off > 0; off >>= 1) {
        if (tid < off) red[tid] += red[tid + off];
        __syncthreads();
    }
    float inv = 1.0f / red[0];
    __syncthreads();

    int hq = tid & 31;
    int is = tid >> 5;
    float4 acc = {0.0f, 0.0f, 0.0f, 0.0f};
    const float4* ob = (const float4*)(out + b * Sn * Hn);
    for (int i = is; i <= t; i += 16) {
        float s = sc[i];
        float4 o4 = ob[i * (Hn / 4) + hq];
        acc.x += s * o4.x; acc.y += s * o4.y;
        acc.z += s * o4.z; acc.w += s * o4.w;
    }
    ((float4*)part[is])[hq] = acc;
    __syncthreads();
    if (tid < Hn) {
        float ssum = 0.0f;
#pragma unroll
        for (int r = 0; r < 16; r++) ssum += part[r][tid];
        ctx[(b * Sn + t) * Hn + tid] = ssum * inv;
    }
}

// ---------------------------------------------------------------------------
// Kernel E: logits = [out, ctx] @ Wf.T + bf. Block per (b,s), 128 threads.
// ---------------------------------------------------------------------------
__global__ __launch_bounds__(128) void k_final(
        const float* __restrict__ out, const float* __restrict__ ctx,
        const float* __restrict__ Wf, const float* __restrict__ bf,
        float* __restrict__ logits) {
    int bs  = blockIdx.x;
    int tid = threadIdx.x;
    __shared__ float oc[2 * Hn];
    oc[tid]      = out[bs * Hn + tid];
    oc[tid + Hn] = ctx[bs * Hn + tid];
    __syncthreads();
    const float4* wr = (const float4*)(Wf + tid * 2 * Hn);
    float acc = bf[tid];
#pragma unroll
    for (int i = 0; i < (2 * Hn) / 4; i++) {
        float4 w4 = wr[i];
        acc += w4.x * oc[4*i] + w4.y * oc[4*i+1] + w4.z * oc[4*i+2] + w4.w * oc[4*i+3];
    }
    logits[bs * Vn + tid] = acc;
}

extern "C" void kernel_launch(void* const* d_in, const int* in_sizes, int n_in,
                              void* d_out, int out_size, void* d_ws, size_t ws_size,
                              hipStream_t stream) {
    const int*   x   = (const int*)d_in[0];
    const float* emb = (const float*)d_in[1];
    const float* Wih = (const float*)d_in[2];
    const float* Whh = (const float*)d_in[3];
    const float* bih = (const float*)d_in[4];
    const float* bhh = (const float*)d_in[5];
    const float* Wq  = (const float*)d_in[6];
    const float* bq  = (const float*)d_in[7];
    const float* Wk  = (const float*)d_in[8];
    const float* bk  = (const float*)d_in[9];
    const float* v   = (const float*)d_in[10];
    const float* Wf  = (const float*)d_in[11];
    const float* bf  = (const float*)d_in[12];

    float* logits = (float*)d_out;                 // (B,S,V) = 262144
    float* hT     = logits + Bn * Sn * Vn;         // (B,H)   = 512
    float* cT     = hT + Bn * Hn;                  // (B,H)   = 512

    float* ws   = (float*)d_ws;
    float* Gtab = ws;                               // V*4H   = 65536 floats
    float* outb = ws + 65536;                       // B*S*H  = 262144
    float* qo   = ws + 65536 + 262144;
    float* ko   = ws + 65536 + 2 * 262144;
    float* ctx  = ws + 65536 + 3 * 262144;

    k_gtab<<<Vn, 512, 0, stream>>>(emb, Wih, bih, bhh, Gtab);
    k_lstm<<<1, 512, 0, stream>>>(Whh, Gtab, x, outb, hT, cT);
    k_qk<<<Bn * Sn, 256, 0, stream>>>(outb, Wq, bq, Wk, bk, qo, ko);
    k_attn<<<Bn * Sn, 512, 0, stream>>>(qo, ko, v, outb, ctx);
    k_final<<<Bn * Sn, 128, 0, stream>>>(outb, ctx, Wf, bf, logits);
}

// Round 8
// 609.444 us; speedup vs baseline: 1.6311x; 1.6311x over previous
//
#include <hip/hip_runtime.h>

#define Vn 128
#define En 32
#define Hn 128
#define Bn 4
#define Sn 512
#define G4H 512   // 4*Hn

typedef _Float16 half8 __attribute__((ext_vector_type(8)));
typedef float    floatx4 __attribute__((ext_vector_type(4)));

__device__ __forceinline__ float fsigmoid(float x) {
    return 1.0f / (1.0f + __expf(-x));
}

__device__ __forceinline__ float ftanh(float x) {
    float ax = fabsf(x);
    float e  = __expf(2.0f * ax);
    float t  = 1.0f - 2.0f / (e + 1.0f);
    return copysignf(t, x);
}

// ---------------------------------------------------------------------------
// Kernel A': Gtab[v][g] = (b_ih+b_hh)[g] + sum_e emb[v][e] * W_ih[g][e]
// ---------------------------------------------------------------------------
__global__ __launch_bounds__(512) void k_gtab(
        const float* __restrict__ emb, const float* __restrict__ Wih,
        const float* __restrict__ bih, const float* __restrict__ bhh,
        float* __restrict__ Gtab) {
    int v = blockIdx.x;
    int g = threadIdx.x;
    __shared__ float e[En];
    if (g < En) e[g] = emb[v * En + g];
    __syncthreads();
    const float4* wr = (const float4*)(Wih + g * En);
    float acc = bih[g] + bhh[g];
#pragma unroll
    for (int i = 0; i < En / 4; i++) {
        float4 w4 = wr[i];
        acc += w4.x * e[4*i] + w4.y * e[4*i+1] + w4.z * e[4*i+2] + w4.w * e[4*i+3];
    }
    Gtab[v * G4H + g] = acc;
}

// ---------------------------------------------------------------------------
// Kernel B (R12): MFMA LSTM, gate-interleaved tiles, ONE barrier/step,
// ZERO-redundancy activation via intra-wave D-transpose.
//
// R11 post-mortem: D layout (4 rows x 1 batch per lane, 4x column
// duplication) made every lane run 4 redundant activation chains ->
// VALU-issue-bound at ~80% per-CU (788us). Fix: the wave's 64 useful
// outputs (16 rows x 4 batches) == 64 lanes. Redistribute d through a
// per-wave LDS scratch (write 4xb128 by cn<4 lanes, waitcnt, read 4xb32
// per lane) -- wave-synchronous, NO barrier. Each lane then runs exactly
// ONE activation chain for its (row jr, batch bb). Keeps R11's single
// end-of-step barrier + double-buffered fp16 hbuf.
// Bank audit: sw write 16 lanes b128 stride-4-words = free; sw read word
// index == lane = 2 lanes/bank = free; hbuf b128 reads worst 2-way = free.
// A-fragments (64 regs) loaded+cvt'd once, MFMA-native from AGPRs (R10).
// ---------------------------------------------------------------------------
__global__ __attribute__((amdgpu_flat_work_group_size(512, 512),
                          amdgpu_waves_per_eu(2, 2)))
void k_lstm(
        const float* __restrict__ Whh, const float* __restrict__ Gtab,
        const int* __restrict__ x,
        float* __restrict__ out, float* __restrict__ hT, float* __restrict__ cT) {
    int tid = threadIdx.x;
    int wv  = tid >> 6;    // wave 0..7: owns j-range [16wv, 16wv+16)
    int l   = tid & 63;
    int cn  = l & 15;      // MFMA A-row within tile / D col (batch if < 4)
    int kg  = l >> 4;      // k-group 0..3
    int cb  = cn & 3;      // clamped batch for B-frag load
    int jr  = l >> 2;      // activation: row within tile (0..15)
    int bb  = l & 3;       // activation: batch
    int aj  = 16 * wv + jr; // activation: global row j

    __shared__ int xb[4][520];                       // padded: bank-spread
    __shared__ alignas(16) _Float16 hbuf[2][4][144]; // h fp16, double-buffered
    __shared__ alignas(16) float sw[8][4][4][16];    // [wave][gate][batch][row16]

    for (int i = tid; i < Bn * Sn; i += 512) xb[i >> 9][i & 511] = x[i];
    for (int i = tid; i < 2 * 4 * 144; i += 512) ((_Float16*)hbuf)[i] = (_Float16)0.0f;

    // ---- A-fragments: af[gate][kc], loaded + converted ONCE ----
    half8 af[4][4];
#pragma unroll
    for (int g = 0; g < 4; g++) {
#pragma unroll
        for (int kc = 0; kc < 4; kc++) {
            int row = g * Hn + 16 * wv + cn;
            int kb  = kc * 32 + kg * 8;
            const float4* p = (const float4*)(Whh + row * Hn + kb);
            float4 lo = p[0], hi = p[1];
            half8 a = { (_Float16)lo.x, (_Float16)lo.y, (_Float16)lo.z, (_Float16)lo.w,
                        (_Float16)hi.x, (_Float16)hi.y, (_Float16)hi.z, (_Float16)hi.w };
            af[g][kc] = a;
        }
    }

    float c_ = 0.f, h_ = 0.f;
    __syncthreads();

    // prefetch step-0 x-path preactivations for THIS lane's (bb, aj)
    float gx0, gx1, gx2, gx3;
    {
        const float* gp = Gtab + xb[bb][0] * G4H + aj;
        gx0 = gp[0]; gx1 = gp[128]; gx2 = gp[256]; gx3 = gp[384];
    }

    int cur = 0;
    for (int s = 0; s < Sn; s++) {
        // B-fragments from hbuf[cur]: col = batch, k = kc*32+kg*8+(0..7)
        half8 bf[4];
#pragma unroll
        for (int kc = 0; kc < 4; kc++)
            bf[kc] = *(const half8*)&hbuf[cur][cb][kc * 32 + kg * 8];

        // 16 MFMAs: 4 gates x 4 K-chunks, fp32 accumulate
        floatx4 d[4];
#pragma unroll
        for (int g = 0; g < 4; g++) {
            floatx4 acc = { 0.f, 0.f, 0.f, 0.f };
#pragma unroll
            for (int kc = 0; kc < 4; kc++)
                acc = __builtin_amdgcn_mfma_f32_16x16x32_f16(af[g][kc], bf[kc], acc, 0, 0, 0);
            d[g] = acc;
        }

        // intra-wave D-transpose through per-wave scratch (no barrier:
        // same-wave ds_write -> waitcnt -> ds_read is wave-synchronous)
        if (cn < 4) {
#pragma unroll
            for (int g = 0; g < 4; g++)
                *(floatx4*)&sw[wv][g][cn][kg * 4] = d[g];
        }

        // prefetch NEXT step's gx while the LDS exchange drains
        int sn = (s + 1 < Sn) ? s + 1 : s;
        const float* gp = Gtab + xb[bb][sn] * G4H + aj;
        float ngx0 = gp[0], ngx1 = gp[128], ngx2 = gp[256], ngx3 = gp[384];

        // each lane: ONE (row,batch) -> one activation chain
        float gi = gx0 + sw[wv][0][bb][jr];
        float gf = gx1 + sw[wv][1][bb][jr];
        float gg = gx2 + sw[wv][2][bb][jr];
        float go = gx3 + sw[wv][3][bb][jr];
        c_ = fsigmoid(gf) * c_ + fsigmoid(gi) * ftanh(gg);
        h_ = fsigmoid(go) * ftanh(c_);

        out[bb * Sn * Hn + s * Hn + aj] = h_;
        hbuf[cur ^ 1][bb][aj] = (_Float16)h_;

        gx0 = ngx0; gx1 = ngx1; gx2 = ngx2; gx3 = ngx3;
        __syncthreads();   // h(s) published; next step reads hbuf[cur^1]
        cur ^= 1;
    }
    hT[bb * Hn + aj] = h_;
    cT[bb * Hn + aj] = c_;
}

// ---------------------------------------------------------------------------
// Kernel C: q = out@Wq.T + bq ; k = out@Wk.T + bk
// ---------------------------------------------------------------------------
__global__ __launch_bounds__(256) void k_qk(
        const float* __restrict__ out, const float* __restrict__ Wq,
        const float* __restrict__ bq, const float* __restrict__ Wk,
        const float* __restrict__ bk, float* __restrict__ qo, float* __restrict__ ko) {
    int bs  = blockIdx.x;
    int tid = threadIdx.x;
    __shared__ float o[Hn];
    if (tid < Hn) o[tid] = out[bs * Hn + tid];
    __syncthreads();
    int h = tid & 127;
    const float* Wm = (tid < Hn) ? Wq : Wk;
    const float* bm = (tid < Hn) ? bq : bk;
    const float4* wr = (const float4*)(Wm + h * Hn);
    float acc = bm[h];
#pragma unroll
    for (int i = 0; i < Hn / 4; i++) {
        float4 w4 = wr[i];
        acc += w4.x * o[4*i] + w4.y * o[4*i+1] + w4.z * o[4*i+2] + w4.w * o[4*i+3];
    }
    float* dst = (tid < Hn) ? qo : ko;
    dst[bs * Hn + h] = acc;
}

// ---------------------------------------------------------------------------
// Kernel D: Bahdanau scores + causal softmax + ctx. Block per (b,t).
// ---------------------------------------------------------------------------
__global__ __launch_bounds__(512) void k_attn(
        const float* __restrict__ qo, const float* __restrict__ ko,
        const float* __restrict__ vvec, const float* __restrict__ out,
        float* __restrict__ ctx) {
    int b   = blockIdx.x >> 9;
    int t   = blockIdx.x & (Sn - 1);
    int tid = threadIdx.x;
    __shared__ float qs[Hn];
    __shared__ float vs[Hn];
    __shared__ float sc[Sn];
    __shared__ float red[512];
    __shared__ float part[16][Hn];

    if (tid < Hn) {
        qs[tid] = qo[(b * Sn + t) * Hn + tid];
        vs[tid] = vvec[tid];
    }
    __syncthreads();

    float a = -1e30f;
    if (tid <= t) {
        const float4* kr = (const float4*)(ko + (b * Sn + tid) * Hn);
        float s = 0.0f;
#pragma unroll
        for (int u = 0; u < Hn / 4; u++) {
            float4 k4 = kr[u];
            s += vs[4*u]   * ftanh(qs[4*u]   + k4.x);
            s += vs[4*u+1] * ftanh(qs[4*u+1] + k4.y);
            s += vs[4*u+2] * ftanh(qs[4*u+2] + k4.z);
            s += vs[4*u+3] * ftanh(qs[4*u+3] + k4.w);
        }
        sc[tid] = s;
        a = s;
    }
    red[tid] = a;
    __syncthreads();
    for (int off = 256; off > 0; off >>= 1) {
        if (tid < off) red[tid] = fmaxf(red[tid], red[tid + off]);
        __syncthreads();
    }
    float m = red[0];
    __syncthreads();

    float ev = 0.0f;
    if (tid <= t) {
        ev = __expf(sc[tid] - m);
        sc[tid] = ev;
    }
    red[tid] = ev;
    __syncthreads();
    for (int off = 256; off > 0; off >>= 1) {
        if (tid < off) red[tid] += red[tid + off];
        __syncthreads();
    }
    float inv = 1.0f / red[0];
    __syncthreads();

    int hq = tid & 31;
    int is = tid >> 5;
    float4 acc = {0.0f, 0.0f, 0.0f, 0.0f};
    const float4* ob = (const float4*)(out + b * Sn * Hn);
    for (int i = is; i <= t; i += 16) {
        float s = sc[i];
        float4 o4 = ob[i * (Hn / 4) + hq];
        acc.x += s * o4.x; acc.y += s * o4.y;
        acc.z += s * o4.z; acc.w += s * o4.w;
    }
    ((float4*)part[is])[hq] = acc;
    __syncthreads();
    if (tid < Hn) {
        float ssum = 0.0f;
#pragma unroll
        for (int r = 0; r < 16; r++) ssum += part[r][tid];
        ctx[(b * Sn + t) * Hn + tid] = ssum * inv;
    }
}

// ---------------------------------------------------------------------------
// Kernel E: logits = [out, ctx] @ Wf.T + bf. Block per (b,s), 128 threads.
// ---------------------------------------------------------------------------
__global__ __launch_bounds__(128) void k_final(
        const float* __restrict__ out, const float* __restrict__ ctx,
        const float* __restrict__ Wf, const float* __restrict__ bf,
        float* __restrict__ logits) {
    int bs  = blockIdx.x;
    int tid = threadIdx.x;
    __shared__ float oc[2 * Hn];
    oc[tid]      = out[bs * Hn + tid];
    oc[tid + Hn] = ctx[bs * Hn + tid];
    __syncthreads();
    const float4* wr = (const float4*)(Wf + tid * 2 * Hn);
    float acc = bf[tid];
#pragma unroll
    for (int i = 0; i < (2 * Hn) / 4; i++) {
        float4 w4 = wr[i];
        acc += w4.x * oc[4*i] + w4.y * oc[4*i+1] + w4.z * oc[4*i+2] + w4.w * oc[4*i+3];
    }
    logits[bs * Vn + tid] = acc;
}

extern "C" void kernel_launch(void* const* d_in, const int* in_sizes, int n_in,
                              void* d_out, int out_size, void* d_ws, size_t ws_size,
                              hipStream_t stream) {
    const int*   x   = (const int*)d_in[0];
    const float* emb = (const float*)d_in[1];
    const float* Wih = (const float*)d_in[2];
    const float* Whh = (const float*)d_in[3];
    const float* bih = (const float*)d_in[4];
    const float* bhh = (const float*)d_in[5];
    const float* Wq  = (const float*)d_in[6];
    const float* bq  = (const float*)d_in[7];
    const float* Wk  = (const float*)d_in[8];
    const float* bk  = (const float*)d_in[9];
    const float* v   = (const float*)d_in[10];
    const float* Wf  = (const float*)d_in[11];
    const float* bf  = (const float*)d_in[12];

    float* logits = (float*)d_out;                 // (B,S,V) = 262144
    float* hT     = logits + Bn * Sn * Vn;         // (B,H)   = 512
    float* cT     = hT + Bn * Hn;                  // (B,H)   = 512

    float* ws   = (float*)d_ws;
    float* Gtab = ws;                               // V*4H   = 65536 floats
    float* outb = ws + 65536;                       // B*S*H  = 262144
    float* qo   = ws + 65536 + 262144;
    float* ko   = ws + 65536 + 2 * 262144;
    float* ctx  = ws + 65536 + 3 * 262144;

    k_gtab<<<Vn, 512, 0, stream>>>(emb, Wih, bih, bhh, Gtab);
    k_lstm<<<1, 512, 0, stream>>>(Whh, Gtab, x, outb, hT, cT);
    k_qk<<<Bn * Sn, 256, 0, stream>>>(outb, Wq, bq, Wk, bk, qo, ko);
    k_attn<<<Bn * Sn, 512, 0, stream>>>(qo, ko, v, outb, ctx);
    k_final<<<Bn * Sn, 128, 0, stream>>>(outb, ctx, Wf, bf, logits);
}

// Round 10
// 581.530 us; speedup vs baseline: 1.7094x; 1.0480x over previous
//
#include <hip/hip_runtime.h>

#define Vn 128
#define En 32
#define Hn 128
#define Bn 4
#define Sn 512
#define G4H 512   // 4*Hn

typedef _Float16 half8 __attribute__((ext_vector_type(8)));
typedef float    floatx4 __attribute__((ext_vector_type(4)));

__device__ __forceinline__ float fsigmoid(float x) {
    return 1.0f / (1.0f + __expf(-x));
}

__device__ __forceinline__ float ftanh(float x) {
    float ax = fabsf(x);
    float e  = __expf(2.0f * ax);
    float t  = 1.0f - 2.0f / (e + 1.0f);
    return copysignf(t, x);
}

// ---------------------------------------------------------------------------
// Kernel A': Gtab, GATE-INTERLEAVED: Gtab[v][j][g] (g fastest) so k_lstm's
// per-step x-path read is ONE float4 per lane instead of 4 strided loads.
// ---------------------------------------------------------------------------
__global__ __launch_bounds__(512) void k_gtab(
        const float* __restrict__ emb, const float* __restrict__ Wih,
        const float* __restrict__ bih, const float* __restrict__ bhh,
        float* __restrict__ Gtab) {
    int v = blockIdx.x;
    int g = threadIdx.x;            // g = gate*128 + j
    __shared__ float e[En];
    if (g < En) e[g] = emb[v * En + g];
    __syncthreads();
    const float4* wr = (const float4*)(Wih + g * En);
    float acc = bih[g] + bhh[g];
#pragma unroll
    for (int i = 0; i < En / 4; i++) {
        float4 w4 = wr[i];
        acc += w4.x * e[4*i] + w4.y * e[4*i+1] + w4.z * e[4*i+2] + w4.w * e[4*i+3];
    }
    Gtab[v * G4H + (g & 127) * 4 + (g >> 7)] = acc;   // [v][j][gate]
}

// ---------------------------------------------------------------------------
// Kernel B (R14 = R13 with DPP direction FIXED): MFMA LSTM; D-transpose via
// DPP row_shr (register-only), one float4 x-path load, ONE barrier/step.
//
// R13 post-mortem: used row_shl (0x104/8/C) which delivers lane i+N's value;
// the transpose needs lane i-4r's value = row_shr:4r (0x114/0x118/0x11C) --
// the canonical AMD scan idiom direction. 3/4 of rows got scrambled (small
// weights kept the error at 2e-2 instead of a blowup). Corrected mapping:
//   dst lane l (l16 = 4r+bb) takes reg r=(l>>2)&3 from lane l-4r  [row_shr]
//   src always >= row base (src l16 = bb), bound_ctrl never triggers.
// Everything else identical to R13 (see R12/R13 notes: 16 MFMAs/step from
// AGPR-resident A-frags, zero-redundancy activation, 1 barrier/step).
// ---------------------------------------------------------------------------
__global__ __attribute__((amdgpu_flat_work_group_size(512, 512),
                          amdgpu_waves_per_eu(2, 2)))
void k_lstm(
        const float* __restrict__ Whh, const float* __restrict__ Gtab,
        const int* __restrict__ x,
        float* __restrict__ out, float* __restrict__ hT, float* __restrict__ cT) {
    int tid = threadIdx.x;
    int wv  = tid >> 6;    // wave 0..7: owns j-range [16wv, 16wv+16)
    int l   = tid & 63;
    int cn  = l & 15;      // MFMA A-row within tile / D col (batch if < 4)
    int kg  = l >> 4;      // k-group 0..3
    int cb  = l & 3;       // batch for B-frag load (4x dup over cn)
    int jr  = l >> 2;      // activation: row within tile (0..15)
    int bb  = l & 3;       // activation: batch
    int aj  = 16 * wv + jr; // activation: global row j

    bool r1 = (l >> 2) & 1;   // select bits for DPP exchange (loop-invariant)
    bool r2 = (l >> 2) & 2;

    __shared__ int xb[4][520];                       // padded: bank-spread
    __shared__ alignas(16) _Float16 hbuf[2][4][144]; // h fp16, double-buffered

    for (int i = tid; i < Bn * Sn; i += 512) xb[i >> 9][i & 511] = x[i];
    for (int i = tid; i < 2 * 4 * 144; i += 512) ((_Float16*)hbuf)[i] = (_Float16)0.0f;

    // ---- A-fragments: af[gate][kc], loaded + converted ONCE ----
    half8 af[4][4];
#pragma unroll
    for (int g = 0; g < 4; g++) {
#pragma unroll
        for (int kc = 0; kc < 4; kc++) {
            int row = g * Hn + 16 * wv + cn;
            int kb  = kc * 32 + kg * 8;
            const float4* p = (const float4*)(Whh + row * Hn + kb);
            float4 lo = p[0], hi = p[1];
            half8 a = { (_Float16)lo.x, (_Float16)lo.y, (_Float16)lo.z, (_Float16)lo.w,
                        (_Float16)hi.x, (_Float16)hi.y, (_Float16)hi.z, (_Float16)hi.w };
            af[g][kc] = a;
        }
    }

    float c_ = 0.f, h_ = 0.f;
    __syncthreads();

    // prefetch step-0 x-path preactivations: ONE float4 (gates interleaved)
    float4 gx4 = *(const float4*)(Gtab + xb[bb][0] * G4H + aj * 4);

    int cur = 0;
    for (int s = 0; s < Sn; s++) {
        // B-fragments from hbuf[cur]: col = batch, k = kc*32+kg*8+(0..7)
        half8 bf[4];
#pragma unroll
        for (int kc = 0; kc < 4; kc++)
            bf[kc] = *(const half8*)&hbuf[cur][cb][kc * 32 + kg * 8];

        // 16 MFMAs: 4 gates x 4 K-chunks, fp32 accumulate
        floatx4 d[4];
#pragma unroll
        for (int g = 0; g < 4; g++) {
            floatx4 acc = { 0.f, 0.f, 0.f, 0.f };
#pragma unroll
            for (int kc = 0; kc < 4; kc++)
                acc = __builtin_amdgcn_mfma_f32_16x16x32_f16(af[g][kc], bf[kc], acc, 0, 0, 0);
            d[g] = acc;
        }

        // prefetch NEXT step's gx (token-only dependence)
        int sn = (s + 1 < Sn) ? s + 1 : s;
        float4 ngx = *(const float4*)(Gtab + xb[bb][sn] * G4H + aj * 4);

        // ---- D-transpose via DPP row_shr (register-only, no barrier) ----
        // dst lane l wants D[row=4*(l>>4)+r][col=l&3] held by lane l-4r,
        // reg r -> row_shr:4r delivers lane (i-4r)'s value to lane i.
        float ex[4];
#pragma unroll
        for (int g = 0; g < 4; g++) {
            float s0 = d[g][0], s1 = d[g][1], s2 = d[g][2], s3 = d[g][3];
            float t1 = __int_as_float(__builtin_amdgcn_update_dpp(
                           0, __float_as_int(s1), 0x114, 0xF, 0xF, false)); // row_shr:4
            float t2 = __int_as_float(__builtin_amdgcn_update_dpp(
                           0, __float_as_int(s2), 0x118, 0xF, 0xF, false)); // row_shr:8
            float t3 = __int_as_float(__builtin_amdgcn_update_dpp(
                           0, __float_as_int(s3), 0x11C, 0xF, 0xF, false)); // row_shr:12
            float lo = r1 ? t1 : s0;
            float hi = r1 ? t3 : t2;
            ex[g] = r2 ? hi : lo;
        }

        // each lane: ONE (row aj, batch bb) activation chain
        float gi = gx4.x + ex[0];
        float gf = gx4.y + ex[1];
        float gg = gx4.z + ex[2];
        float go = gx4.w + ex[3];
        c_ = fsigmoid(gf) * c_ + fsigmoid(gi) * ftanh(gg);
        h_ = fsigmoid(go) * ftanh(c_);

        out[bb * Sn * Hn + s * Hn + aj] = h_;
        hbuf[cur ^ 1][bb][aj] = (_Float16)h_;

        gx4 = ngx;
        __syncthreads();   // h(s) published; next step reads hbuf[cur^1]
        cur ^= 1;
    }
    hT[bb * Hn + aj] = h_;
    cT[bb * Hn + aj] = c_;
}

// ---------------------------------------------------------------------------
// Kernel C: q = out@Wq.T + bq ; k = out@Wk.T + bk
// ---------------------------------------------------------------------------
__global__ __launch_bounds__(256) void k_qk(
        const float* __restrict__ out, const float* __restrict__ Wq,
        const float* __restrict__ bq, const float* __restrict__ Wk,
        const float* __restrict__ bk, float* __restrict__ qo, float* __restrict__ ko) {
    int bs  = blockIdx.x;
    int tid = threadIdx.x;
    __shared__ float o[Hn];
    if (tid < Hn) o[tid] = out[bs * Hn + tid];
    __syncthreads();
    int h = tid & 127;
    const float* Wm = (tid < Hn) ? Wq : Wk;
    const float* bm = (tid < Hn) ? bq : bk;
    const float4* wr = (const float4*)(Wm + h * Hn);
    float acc = bm[h];
#pragma unroll
    for (int i = 0; i < Hn / 4; i++) {
        float4 w4 = wr[i];
        acc += w4.x * o[4*i] + w4.y * o[4*i+1] + w4.z * o[4*i+2] + w4.w * o[4*i+3];
    }
    float* dst = (tid < Hn) ? qo : ko;
    dst[bs * Hn + h] = acc;
}

// ---------------------------------------------------------------------------
// Kernel D (R13): Bahdanau scores + causal softmax + ctx. Block per (b,t).
// Reductions via wave __shfl_xor + 8-entry LDS combine: 4 barriers/block.
// ---------------------------------------------------------------------------
__global__ __launch_bounds__(512) void k_attn(
        const float* __restrict__ qo, const float* __restrict__ ko,
        const float* __restrict__ vvec, const float* __restrict__ out,
        float* __restrict__ ctx) {
    int b   = blockIdx.x >> 9;
    int t   = blockIdx.x & (Sn - 1);
    int tid = threadIdx.x;
    int wv  = tid >> 6;
    __shared__ float qs[Hn];
    __shared__ float vs[Hn];
    __shared__ float sc[Sn];
    __shared__ float wmax[8];
    __shared__ float wsum[8];
    __shared__ float part[16][Hn];

    if (tid < Hn) {
        qs[tid] = qo[(b * Sn + t) * Hn + tid];
        vs[tid] = vvec[tid];
    }
    __syncthreads();

    // --- scores: thread tid handles key index i = tid (if <= t) ---
    float a = -1e30f;
    if (tid <= t) {
        const float4* kr = (const float4*)(ko + (b * Sn + tid) * Hn);
        float s = 0.0f;
#pragma unroll
        for (int u = 0; u < Hn / 4; u++) {
            float4 k4 = kr[u];
            s += vs[4*u]   * ftanh(qs[4*u]   + k4.x);
            s += vs[4*u+1] * ftanh(qs[4*u+1] + k4.y);
            s += vs[4*u+2] * ftanh(qs[4*u+2] + k4.z);
            s += vs[4*u+3] * ftanh(qs[4*u+3] + k4.w);
        }
        sc[tid] = s;
        a = s;
    }
#pragma unroll
    for (int off = 32; off > 0; off >>= 1) a = fmaxf(a, __shfl_xor(a, off));
    if ((tid & 63) == 0) wmax[wv] = a;
    __syncthreads();
    float m = wmax[0];
#pragma unroll
    for (int r = 1; r < 8; r++) m = fmaxf(m, wmax[r]);

    float ev = 0.0f;
    if (tid <= t) {
        ev = __expf(sc[tid] - m);
        sc[tid] = ev;
    }
    float ssum = ev;
#pragma unroll
    for (int off = 32; off > 0; off >>= 1) ssum += __shfl_xor(ssum, off);
    if ((tid & 63) == 0) wsum[wv] = ssum;
    __syncthreads();
    float tot = wsum[0];
#pragma unroll
    for (int r = 1; r < 8; r++) tot += wsum[r];
    float inv = 1.0f / tot;

    // --- ctx: i-slice = tid>>5 (16 slices), float4 column = tid&31 ---
    int hq = tid & 31;
    int is = tid >> 5;
    float4 acc = {0.0f, 0.0f, 0.0f, 0.0f};
    const float4* ob = (const float4*)(out + b * Sn * Hn);
    for (int i = is; i <= t; i += 16) {
        float s = sc[i];
        float4 o4 = ob[i * (Hn / 4) + hq];
        acc.x += s * o4.x; acc.y += s * o4.y;
        acc.z += s * o4.z; acc.w += s * o4.w;
    }
    ((float4*)part[is])[hq] = acc;
    __syncthreads();
    if (tid < Hn) {
        float sum2 = 0.0f;
#pragma unroll
        for (int r = 0; r < 16; r++) sum2 += part[r][tid];
        ctx[(b * Sn + t) * Hn + tid] = sum2 * inv;
    }
}

// ---------------------------------------------------------------------------
// Kernel E: logits = [out, ctx] @ Wf.T + bf. Block per (b,s), 128 threads.
// ---------------------------------------------------------------------------
__global__ __launch_bounds__(128) void k_final(
        const float* __restrict__ out, const float* __restrict__ ctx,
        const float* __restrict__ Wf, const float* __restrict__ bf,
        float* __restrict__ logits) {
    int bs  = blockIdx.x;
    int tid = threadIdx.x;
    __shared__ float oc[2 * Hn];
    oc[tid]      = out[bs * Hn + tid];
    oc[tid + Hn] = ctx[bs * Hn + tid];
    __syncthreads();
    const float4* wr = (const float4*)(Wf + tid * 2 * Hn);
    float acc = bf[tid];
#pragma unroll
    for (int i = 0; i < (2 * Hn) / 4; i++) {
        float4 w4 = wr[i];
        acc += w4.x * oc[4*i] + w4.y * oc[4*i+1] + w4.z * oc[4*i+2] + w4.w * oc[4*i+3];
    }
    logits[bs * Vn + tid] = acc;
}

extern "C" void kernel_launch(void* const* d_in, const int* in_sizes, int n_in,
                              void* d_out, int out_size, void* d_ws, size_t ws_size,
                              hipStream_t stream) {
    const int*   x   = (const int*)d_in[0];
    const float* emb = (const float*)d_in[1];
    const float* Wih = (const float*)d_in[2];
    const float* Whh = (const float*)d_in[3];
    const float* bih = (const float*)d_in[4];
    const float* bhh = (const float*)d_in[5];
    const float* Wq  = (const float*)d_in[6];
    const float* bq  = (const float*)d_in[7];
    const float* Wk  = (const float*)d_in[8];
    const float* bk  = (const float*)d_in[9];
    const float* v   = (const float*)d_in[10];
    const float* Wf  = (const float*)d_in[11];
    const float* bf  = (const float*)d_in[12];

    float* logits = (float*)d_out;                 // (B,S,V) = 262144
    float* hT     = logits + Bn * Sn * Vn;         // (B,H)   = 512
    float* cT     = hT + Bn * Hn;                  // (B,H)   = 512

    float* ws   = (float*)d_ws;
    float* Gtab = ws;                               // V*4H   = 65536 floats
    float* outb = ws + 65536;                       // B*S*H  = 262144
    float* qo   = ws + 65536 + 262144;
    float* ko   = ws + 65536 + 2 * 262144;
    float* ctx  = ws + 65536 + 3 * 262144;

    k_gtab<<<Vn, 512, 0, stream>>>(emb, Wih, bih, bhh, Gtab);
    k_lstm<<<1, 512, 0, stream>>>(Whh, Gtab, x, outb, hT, cT);
    k_qk<<<Bn * Sn, 256, 0, stream>>>(outb, Wq, bq, Wk, bk, qo, ko);
    k_attn<<<Bn * Sn, 512, 0, stream>>>(qo, ko, v, outb, ctx);
    k_final<<<Bn * Sn, 128, 0, stream>>>(outb, ctx, Wf, bf, logits);
}

// Round 11
// 530.250 us; speedup vs baseline: 1.8747x; 1.0967x over previous
//
#include <hip/hip_runtime.h>

#define Vn 128
#define En 32
#define Hn 128
#define Bn 4
#define Sn 512
#define G4H 512   // 4*Hn

typedef _Float16 half8 __attribute__((ext_vector_type(8)));
typedef float    floatx4 __attribute__((ext_vector_type(4)));

__device__ __forceinline__ float fsigmoid(float x) {
    return 1.0f / (1.0f + __expf(-x));
}

__device__ __forceinline__ float ftanh(float x) {
    float ax = fabsf(x);
    float e  = __expf(2.0f * ax);
    float t  = 1.0f - 2.0f / (e + 1.0f);
    return copysignf(t, x);
}

// ---------------------------------------------------------------------------
// Kernel A': Gtab, GATE-INTERLEAVED: Gtab[v][j][g] (g fastest) so k_lstm's
// per-step x-path read is ONE float4 per lane instead of 4 strided loads.
// ---------------------------------------------------------------------------
__global__ __launch_bounds__(512) void k_gtab(
        const float* __restrict__ emb, const float* __restrict__ Wih,
        const float* __restrict__ bih, const float* __restrict__ bhh,
        float* __restrict__ Gtab) {
    int v = blockIdx.x;
    int g = threadIdx.x;            // g = gate*128 + j
    __shared__ float e[En];
    if (g < En) e[g] = emb[v * En + g];
    __syncthreads();
    const float4* wr = (const float4*)(Wih + g * En);
    float acc = bih[g] + bhh[g];
#pragma unroll
    for (int i = 0; i < En / 4; i++) {
        float4 w4 = wr[i];
        acc += w4.x * e[4*i] + w4.y * e[4*i+1] + w4.z * e[4*i+2] + w4.w * e[4*i+3];
    }
    Gtab[v * G4H + (g & 127) * 4 + (g >> 7)] = acc;   // [v][j][gate]
}

// ---------------------------------------------------------------------------
// Kernel B (R15): MFMA LSTM. Two deletions vs R14, both derived not guessed:
//
// 1. NO exchange at all. Since the B-frag load replicates batches across the
//    16 MFMA columns (col c = batch c&3), lane l's own D reg r=(l>>2)&3 is
//    D[row 4kg+r][col l&15] = (row jr, batch bb) -- bit-identical to what
//    R14's row_shr pulled from lane l-4r. The DPP exchange was moving exact
//    duplicates. Replaced by 3 loop-invariant cndmask selects per gate.
//
// 2. Raw barrier WITHOUT vmcnt drain. __syncthreads() emits s_waitcnt
//    vmcnt(0) lgkmcnt(0) before s_barrier -> the scattered per-step `out`
//    store's L2 latency (~200-300cy) was serialized into every step. The
//    only cross-wave hazard is the LDS hbuf write -> a single asm block
//    "s_waitcnt lgkmcnt(0); s_barrier" (memory clobber: no memory op can
//    cross) suffices. Stores fire-and-forget; the gx prefetch has a full
//    step of slack before its compiler-inserted vmcnt wait.
// ---------------------------------------------------------------------------
__global__ __attribute__((amdgpu_flat_work_group_size(512, 512),
                          amdgpu_waves_per_eu(2, 2)))
void k_lstm(
        const float* __restrict__ Whh, const float* __restrict__ Gtab,
        const int* __restrict__ x,
        float* __restrict__ out, float* __restrict__ hT, float* __restrict__ cT) {
    int tid = threadIdx.x;
    int wv  = tid >> 6;    // wave 0..7: owns j-range [16wv, 16wv+16)
    int l   = tid & 63;
    int cn  = l & 15;      // MFMA A-row within tile
    int kg  = l >> 4;      // k-group 0..3
    int cb  = l & 3;       // batch for B-frag load (col c = batch c&3)
    int jr  = l >> 2;      // activation: row within tile (0..15) = 4kg + r
    int bb  = l & 3;       // activation: batch
    int aj  = 16 * wv + jr; // activation: global row j

    bool r1 = (l >> 2) & 1;   // loop-invariant select bits: r = (l>>2)&3
    bool r2 = (l >> 2) & 2;

    __shared__ int xb[4][520];                       // padded: bank-spread
    __shared__ alignas(16) _Float16 hbuf[2][4][144]; // h fp16, double-buffered

    for (int i = tid; i < Bn * Sn; i += 512) xb[i >> 9][i & 511] = x[i];
    for (int i = tid; i < 2 * 4 * 144; i += 512) ((_Float16*)hbuf)[i] = (_Float16)0.0f;

    // ---- A-fragments: af[gate][kc], loaded + converted ONCE ----
    half8 af[4][4];
#pragma unroll
    for (int g = 0; g < 4; g++) {
#pragma unroll
        for (int kc = 0; kc < 4; kc++) {
            int row = g * Hn + 16 * wv + cn;
            int kb  = kc * 32 + kg * 8;
            const float4* p = (const float4*)(Whh + row * Hn + kb);
            float4 lo = p[0], hi = p[1];
            half8 a = { (_Float16)lo.x, (_Float16)lo.y, (_Float16)lo.z, (_Float16)lo.w,
                        (_Float16)hi.x, (_Float16)hi.y, (_Float16)hi.z, (_Float16)hi.w };
            af[g][kc] = a;
        }
    }

    float c_ = 0.f, h_ = 0.f;
    __syncthreads();

    // prefetch step-0 x-path preactivations: ONE float4 (gates interleaved)
    float4 gx4 = *(const float4*)(Gtab + xb[bb][0] * G4H + aj * 4);

    int cur = 0;
    for (int s = 0; s < Sn; s++) {
        // B-fragments from hbuf[cur]: col = batch, k = kc*32+kg*8+(0..7)
        half8 bf[4];
#pragma unroll
        for (int kc = 0; kc < 4; kc++)
            bf[kc] = *(const half8*)&hbuf[cur][cb][kc * 32 + kg * 8];

        // 16 MFMAs: 4 gates x 4 K-chunks, fp32 accumulate
        floatx4 d[4];
#pragma unroll
        for (int g = 0; g < 4; g++) {
            floatx4 acc = { 0.f, 0.f, 0.f, 0.f };
#pragma unroll
            for (int kc = 0; kc < 4; kc++)
                acc = __builtin_amdgcn_mfma_f32_16x16x32_f16(af[g][kc], bf[kc], acc, 0, 0, 0);
            d[g] = acc;
        }

        // prefetch NEXT step's gx (token-only dependence)
        int sn = (s + 1 < Sn) ? s + 1 : s;
        float4 ngx = *(const float4*)(Gtab + xb[bb][sn] * G4H + aj * 4);

        // direct select: lane's own reg r = (l>>2)&3 IS (row jr, batch bb)
        float ex[4];
#pragma unroll
        for (int g = 0; g < 4; g++) {
            float lo = r1 ? d[g][1] : d[g][0];
            float hi = r1 ? d[g][3] : d[g][2];
            ex[g] = r2 ? hi : lo;
        }

        // each lane: ONE (row aj, batch bb) activation chain
        float gi = gx4.x + ex[0];
        float gf = gx4.y + ex[1];
        float gg = gx4.z + ex[2];
        float go = gx4.w + ex[3];
        c_ = fsigmoid(gf) * c_ + fsigmoid(gi) * ftanh(gg);
        h_ = fsigmoid(go) * ftanh(c_);

        out[bb * Sn * Hn + s * Hn + aj] = h_;   // fire-and-forget (no drain)
        hbuf[cur ^ 1][bb][aj] = (_Float16)h_;

        gx4 = ngx;
        // LDS-only barrier: hbuf write visible to all waves; vmcnt NOT
        // drained (the store retires during the next step's ~1300 cycles).
        asm volatile("s_waitcnt lgkmcnt(0)\n\ts_barrier" ::: "memory");
        cur ^= 1;
    }
    hT[bb * Hn + aj] = h_;
    cT[bb * Hn + aj] = c_;
}

// ---------------------------------------------------------------------------
// Kernel C: q = out@Wq.T + bq ; k = out@Wk.T + bk
// ---------------------------------------------------------------------------
__global__ __launch_bounds__(256) void k_qk(
        const float* __restrict__ out, const float* __restrict__ Wq,
        const float* __restrict__ bq, const float* __restrict__ Wk,
        const float* __restrict__ bk, float* __restrict__ qo, float* __restrict__ ko) {
    int bs  = blockIdx.x;
    int tid = threadIdx.x;
    __shared__ float o[Hn];
    if (tid < Hn) o[tid] = out[bs * Hn + tid];
    __syncthreads();
    int h = tid & 127;
    const float* Wm = (tid < Hn) ? Wq : Wk;
    const float* bm = (tid < Hn) ? bq : bk;
    const float4* wr = (const float4*)(Wm + h * Hn);
    float acc = bm[h];
#pragma unroll
    for (int i = 0; i < Hn / 4; i++) {
        float4 w4 = wr[i];
        acc += w4.x * o[4*i] + w4.y * o[4*i+1] + w4.z * o[4*i+2] + w4.w * o[4*i+3];
    }
    float* dst = (tid < Hn) ? qo : ko;
    dst[bs * Hn + h] = acc;
}

// ---------------------------------------------------------------------------
// Kernel D: Bahdanau scores + causal softmax + ctx. Block per (b,t).
// Reductions via wave __shfl_xor + 8-entry LDS combine.
// ---------------------------------------------------------------------------
__global__ __launch_bounds__(512) void k_attn(
        const float* __restrict__ qo, const float* __restrict__ ko,
        const float* __restrict__ vvec, const float* __restrict__ out,
        float* __restrict__ ctx) {
    int b   = blockIdx.x >> 9;
    int t   = blockIdx.x & (Sn - 1);
    int tid = threadIdx.x;
    int wv  = tid >> 6;
    __shared__ float qs[Hn];
    __shared__ float vs[Hn];
    __shared__ float sc[Sn];
    __shared__ float wmax[8];
    __shared__ float wsum[8];
    __shared__ float part[16][Hn];

    if (tid < Hn) {
        qs[tid] = qo[(b * Sn + t) * Hn + tid];
        vs[tid] = vvec[tid];
    }
    __syncthreads();

    // --- scores: thread tid handles key index i = tid (if <= t) ---
    float a = -1e30f;
    if (tid <= t) {
        const float4* kr = (const float4*)(ko + (b * Sn + tid) * Hn);
        float s = 0.0f;
#pragma unroll
        for (int u = 0; u < Hn / 4; u++) {
            float4 k4 = kr[u];
            s += vs[4*u]   * ftanh(qs[4*u]   + k4.x);
            s += vs[4*u+1] * ftanh(qs[4*u+1] + k4.y);
            s += vs[4*u+2] * ftanh(qs[4*u+2] + k4.z);
            s += vs[4*u+3] * ftanh(qs[4*u+3] + k4.w);
        }
        sc[tid] = s;
        a = s;
    }
#pragma unroll
    for (int off = 32; off > 0; off >>= 1) a = fmaxf(a, __shfl_xor(a, off));
    if ((tid & 63) == 0) wmax[wv] = a;
    __syncthreads();
    float m = wmax[0];
#pragma unroll
    for (int r = 1; r < 8; r++) m = fmaxf(m, wmax[r]);

    float ev = 0.0f;
    if (tid <= t) {
        ev = __expf(sc[tid] - m);
        sc[tid] = ev;
    }
    float ssum = ev;
#pragma unroll
    for (int off = 32; off > 0; off >>= 1) ssum += __shfl_xor(ssum, off);
    if ((tid & 63) == 0) wsum[wv] = ssum;
    __syncthreads();
    float tot = wsum[0];
#pragma unroll
    for (int r = 1; r < 8; r++) tot += wsum[r];
    float inv = 1.0f / tot;

    // --- ctx: i-slice = tid>>5 (16 slices), float4 column = tid&31 ---
    int hq = tid & 31;
    int is = tid >> 5;
    float4 acc = {0.0f, 0.0f, 0.0f, 0.0f};
    const float4* ob = (const float4*)(out + b * Sn * Hn);
    for (int i = is; i <= t; i += 16) {
        float s = sc[i];
        float4 o4 = ob[i * (Hn / 4) + hq];
        acc.x += s * o4.x; acc.y += s * o4.y;
        acc.z += s * o4.z; acc.w += s * o4.w;
    }
    ((float4*)part[is])[hq] = acc;
    __syncthreads();
    if (tid < Hn) {
        float sum2 = 0.0f;
#pragma unroll
        for (int r = 0; r < 16; r++) sum2 += part[r][tid];
        ctx[(b * Sn + t) * Hn + tid] = sum2 * inv;
    }
}

// ---------------------------------------------------------------------------
// Kernel E: logits = [out, ctx] @ Wf.T + bf. Block per (b,s), 128 threads.
// ---------------------------------------------------------------------------
__global__ __launch_bounds__(128) void k_final(
        const float* __restrict__ out, const float* __restrict__ ctx,
        const float* __restrict__ Wf, const float* __restrict__ bf,
        float* __restrict__ logits) {
    int bs  = blockIdx.x;
    int tid = threadIdx.x;
    __shared__ float oc[2 * Hn];
    oc[tid]      = out[bs * Hn + tid];
    oc[tid + Hn] = ctx[bs * Hn + tid];
    __syncthreads();
    const float4* wr = (const float4*)(Wf + tid * 2 * Hn);
    float acc = bf[tid];
#pragma unroll
    for (int i = 0; i < (2 * Hn) / 4; i++) {
        float4 w4 = wr[i];
        acc += w4.x * oc[4*i] + w4.y * oc[4*i+1] + w4.z * oc[4*i+2] + w4.w * oc[4*i+3];
    }
    logits[bs * Vn + tid] = acc;
}

extern "C" void kernel_launch(void* const* d_in, const int* in_sizes, int n_in,
                              void* d_out, int out_size, void* d_ws, size_t ws_size,
                              hipStream_t stream) {
    const int*   x   = (const int*)d_in[0];
    const float* emb = (const float*)d_in[1];
    const float* Wih = (const float*)d_in[2];
    const float* Whh = (const float*)d_in[3];
    const float* bih = (const float*)d_in[4];
    const float* bhh = (const float*)d_in[5];
    const float* Wq  = (const float*)d_in[6];
    const float* bq  = (const float*)d_in[7];
    const float* Wk  = (const float*)d_in[8];
    const float* bk  = (const float*)d_in[9];
    const float* v   = (const float*)d_in[10];
    const float* Wf  = (const float*)d_in[11];
    const float* bf  = (const float*)d_in[12];

    float* logits = (float*)d_out;                 // (B,S,V) = 262144
    float* hT     = logits + Bn * Sn * Vn;         // (B,H)   = 512
    float* cT     = hT + Bn * Hn;                  // (B,H)   = 512

    float* ws   = (float*)d_ws;
    float* Gtab = ws;                               // V*4H   = 65536 floats
    float* outb = ws + 65536;                       // B*S*H  = 262144
    float* qo   = ws + 65536 + 262144;
    float* ko   = ws + 65536 + 2 * 262144;
    float* ctx  = ws + 65536 + 3 * 262144;

    k_gtab<<<Vn, 512, 0, stream>>>(emb, Wih, bih, bhh, Gtab);
    k_lstm<<<1, 512, 0, stream>>>(Whh, Gtab, x, outb, hT, cT);
    k_qk<<<Bn * Sn, 256, 0, stream>>>(outb, Wq, bq, Wk, bk, qo, ko);
    k_attn<<<Bn * Sn, 512, 0, stream>>>(qo, ko, v, outb, ctx);
    k_final<<<Bn * Sn, 128, 0, stream>>>(outb, ctx, Wf, bf, logits);
}

// Round 12
// 517.986 us; speedup vs baseline: 1.9190x; 1.0237x over previous
//
#include <hip/hip_runtime.h>

#define Vn 128
#define En 32
#define Hn 128
#define Bn 4
#define Sn 512
#define G4H 512   // 4*Hn

typedef _Float16 half8 __attribute__((ext_vector_type(8)));
typedef float    floatx4 __attribute__((ext_vector_type(4)));

__device__ __forceinline__ float fsigmoid(float x) {
    return 1.0f / (1.0f + __expf(-x));
}

// tanh without abs/copysign: 1 - 2/(e^{2x}+1). e^{2x} underflows to 0 (x<<0)
// -> -1, overflows to inf (x>>0) -> +1; never NaN. Same cancellation class
// as the abs-variant near 0 (absolute error ~1e-8, irrelevant at 4e-3 thr).
__device__ __forceinline__ float ftanh(float x) {
    float e = __expf(2.0f * x);
    return 1.0f - 2.0f / (e + 1.0f);
}

// ---------------------------------------------------------------------------
// Kernel A': Gtab, GATE-INTERLEAVED: Gtab[v][j][g] (g fastest) so k_lstm's
// per-step x-path read is ONE float4 per lane.
// ---------------------------------------------------------------------------
__global__ __launch_bounds__(512) void k_gtab(
        const float* __restrict__ emb, const float* __restrict__ Wih,
        const float* __restrict__ bih, const float* __restrict__ bhh,
        float* __restrict__ Gtab) {
    int v = blockIdx.x;
    int g = threadIdx.x;            // g = gate*128 + j
    __shared__ float e[En];
    if (g < En) e[g] = emb[v * En + g];
    __syncthreads();
    const float4* wr = (const float4*)(Wih + g * En);
    float acc = bih[g] + bhh[g];
#pragma unroll
    for (int i = 0; i < En / 4; i++) {
        float4 w4 = wr[i];
        acc += w4.x * e[4*i] + w4.y * e[4*i+1] + w4.z * e[4*i+2] + w4.w * e[4*i+3];
    }
    Gtab[v * G4H + (g & 127) * 4 + (g >> 7)] = acc;   // [v][j][gate]
}

// ---------------------------------------------------------------------------
// Kernel B (R16 = R15 + instruction diet): MFMA LSTM, VALU-issue-bound, so
// every deleted instruction is time:
//  * xb holds PRE-SCALED byte offsets (x*2048): gx addr = ds_read + 64b add
//  * out store via incremented pointer (no per-step address math)
//  * #pragma unroll 2: hbuf[s&1] indices become compile-time constants
//  * xb[.][512] sentinel removes the s+1 clamp cmp/cndmask
//  * ftanh without abs/copysign (-6 instrs/step)
// Core structure unchanged from R15 (16 MFMAs from AGPR-resident A-frags,
// direct D-reg select, LDS-only barrier without vmcnt drain).
// ---------------------------------------------------------------------------
__global__ __attribute__((amdgpu_flat_work_group_size(512, 512),
                          amdgpu_waves_per_eu(2, 2)))
void k_lstm(
        const float* __restrict__ Whh, const float* __restrict__ Gtab,
        const int* __restrict__ x,
        float* __restrict__ out, float* __restrict__ hT, float* __restrict__ cT) {
    int tid = threadIdx.x;
    int wv  = tid >> 6;    // wave 0..7: owns j-range [16wv, 16wv+16)
    int l   = tid & 63;
    int cn  = l & 15;      // MFMA A-row within tile
    int kg  = l >> 4;      // k-group 0..3
    int cb  = l & 3;       // batch for B-frag load (col c = batch c&3)
    int jr  = l >> 2;      // activation: row within tile (0..15)
    int bb  = l & 3;       // activation: batch
    int aj  = 16 * wv + jr; // activation: global row j

    bool r1 = (l >> 2) & 1;   // loop-invariant select bits: r = (l>>2)&3
    bool r2 = (l >> 2) & 2;

    __shared__ int xb[4][520];                       // PRE-SCALED byte offsets
    __shared__ alignas(16) _Float16 hbuf[2][4][144]; // h fp16, double-buffered

    for (int i = tid; i < Bn * Sn; i += 512) xb[i >> 9][i & 511] = x[i] * 2048;
    if (tid < 4) xb[tid][512] = 0;                   // sentinel for s=511 prefetch
    for (int i = tid; i < 2 * 4 * 144; i += 512) ((_Float16*)hbuf)[i] = (_Float16)0.0f;

    // ---- A-fragments: af[gate][kc], loaded + converted ONCE ----
    half8 af[4][4];
#pragma unroll
    for (int g = 0; g < 4; g++) {
#pragma unroll
        for (int kc = 0; kc < 4; kc++) {
            int row = g * Hn + 16 * wv + cn;
            int kb  = kc * 32 + kg * 8;
            const float4* p = (const float4*)(Whh + row * Hn + kb);
            float4 lo = p[0], hi = p[1];
            half8 a = { (_Float16)lo.x, (_Float16)lo.y, (_Float16)lo.z, (_Float16)lo.w,
                        (_Float16)hi.x, (_Float16)hi.y, (_Float16)hi.z, (_Float16)hi.w };
            af[g][kc] = a;
        }
    }

    float c_ = 0.f, h_ = 0.f;
    const char* gbase = (const char*)Gtab + aj * 16;   // + xb byte offset
    float* outp = out + bb * Sn * Hn + aj;
    __syncthreads();

    float4 gx4 = *(const float4*)(gbase + xb[bb][0]);

#pragma unroll 2
    for (int s = 0; s < Sn; s++) {
        // B-fragments from hbuf[s&1]: col = batch, k = kc*32+kg*8+(0..7)
        half8 bf[4];
#pragma unroll
        for (int kc = 0; kc < 4; kc++)
            bf[kc] = *(const half8*)&hbuf[s & 1][cb][kc * 32 + kg * 8];

        // 16 MFMAs: 4 gates x 4 K-chunks, fp32 accumulate
        floatx4 d[4];
#pragma unroll
        for (int g = 0; g < 4; g++) {
            floatx4 acc = { 0.f, 0.f, 0.f, 0.f };
#pragma unroll
            for (int kc = 0; kc < 4; kc++)
                acc = __builtin_amdgcn_mfma_f32_16x16x32_f16(af[g][kc], bf[kc], acc, 0, 0, 0);
            d[g] = acc;
        }

        // prefetch NEXT step's gx (sentinel makes s=511 safe)
        float4 ngx = *(const float4*)(gbase + xb[bb][s + 1]);

        // direct select: lane's own reg r = (l>>2)&3 IS (row jr, batch bb)
        float ex[4];
#pragma unroll
        for (int g = 0; g < 4; g++) {
            float lo = r1 ? d[g][1] : d[g][0];
            float hi = r1 ? d[g][3] : d[g][2];
            ex[g] = r2 ? hi : lo;
        }

        float gi = gx4.x + ex[0];
        float gf = gx4.y + ex[1];
        float gg = gx4.z + ex[2];
        float go = gx4.w + ex[3];
        c_ = fsigmoid(gf) * c_ + fsigmoid(gi) * ftanh(gg);
        h_ = fsigmoid(go) * ftanh(c_);

        *outp = h_;  outp += Hn;                 // fire-and-forget
        hbuf[(s & 1) ^ 1][bb][aj] = (_Float16)h_;

        gx4 = ngx;
        // LDS-only barrier: hbuf visible to all waves; vmcnt NOT drained.
        asm volatile("s_waitcnt lgkmcnt(0)\n\ts_barrier" ::: "memory");
    }
    hT[bb * Hn + aj] = h_;
    cT[bb * Hn + aj] = c_;
}

// ---------------------------------------------------------------------------
// Kernel C (R16): K-only GEMV. ko = out@Wk.T + bk. Block per (b,s), 128 thr.
// (q moved into k_attn; qo round-trip deleted.)
// ---------------------------------------------------------------------------
__global__ __launch_bounds__(128) void k_k(
        const float* __restrict__ out, const float* __restrict__ Wk,
        const float* __restrict__ bk, float* __restrict__ ko) {
    int bs  = blockIdx.x;
    int tid = threadIdx.x;
    __shared__ float o[Hn];
    o[tid] = out[bs * Hn + tid];
    __syncthreads();
    const float4* wr = (const float4*)(Wk + tid * Hn);
    float acc = bk[tid];
#pragma unroll
    for (int i = 0; i < Hn / 4; i++) {
        float4 w4 = wr[i];
        acc += w4.x * o[4*i] + w4.y * o[4*i+1] + w4.z * o[4*i+2] + w4.w * o[4*i+3];
    }
    ko[bs * Hn + tid] = acc;
}

// ---------------------------------------------------------------------------
// Kernel D (R16): FUSED q-GEMV + Bahdanau scores + causal softmax + ctx +
// final logits GEMV. Block per (b,t), 512 threads. ctx never leaves LDS;
// k_final and the qo/ctx global round-trips are deleted.
// ---------------------------------------------------------------------------
__global__ __launch_bounds__(512) void k_attn(
        const float* __restrict__ ko, const float* __restrict__ vvec,
        const float* __restrict__ out,
        const float* __restrict__ Wq, const float* __restrict__ bq,
        const float* __restrict__ Wf, const float* __restrict__ bf,
        float* __restrict__ logits) {
    int b   = blockIdx.x >> 9;
    int t   = blockIdx.x & (Sn - 1);
    int tid = threadIdx.x;
    int wv  = tid >> 6;
    __shared__ float qs[Hn];
    __shared__ float vs[Hn];
    __shared__ float oc[2 * Hn];   // [out_t | ctx_t]
    __shared__ float sc[Sn];
    __shared__ float wmax[8];
    __shared__ float wsum[8];
    __shared__ float part[16][Hn];

    if (tid < Hn) {
        oc[tid] = out[(b * Sn + t) * Hn + tid];
        vs[tid] = vvec[tid];
    }
    __syncthreads();

    // --- q_t = bq + Wq @ out_t: thread (h = tid&127, kq = tid>>7) ---
    {
        int h = tid & 127, kq = tid >> 7;
        const float4* wr = (const float4*)(Wq + h * Hn + kq * 32);
        const float* ob = oc + kq * 32;
        float a = 0.0f;
#pragma unroll
        for (int i = 0; i < 8; i++) {
            float4 w4 = wr[i];
            a += w4.x * ob[4*i] + w4.y * ob[4*i+1] + w4.z * ob[4*i+2] + w4.w * ob[4*i+3];
        }
        part[kq][h] = a;
    }
    __syncthreads();
    if (tid < Hn)
        qs[tid] = bq[tid] + part[0][tid] + part[1][tid] + part[2][tid] + part[3][tid];
    __syncthreads();

    // --- scores: thread tid handles key index i = tid (if <= t) ---
    float a = -1e30f;
    if (tid <= t) {
        const float4* kr = (const float4*)(ko + (b * Sn + tid) * Hn);
        float s = 0.0f;
#pragma unroll
        for (int u = 0; u < Hn / 4; u++) {
            float4 k4 = kr[u];
            s += vs[4*u]   * ftanh(qs[4*u]   + k4.x);
            s += vs[4*u+1] * ftanh(qs[4*u+1] + k4.y);
            s += vs[4*u+2] * ftanh(qs[4*u+2] + k4.z);
            s += vs[4*u+3] * ftanh(qs[4*u+3] + k4.w);
        }
        sc[tid] = s;
        a = s;
    }
#pragma unroll
    for (int off = 32; off > 0; off >>= 1) a = fmaxf(a, __shfl_xor(a, off));
    if ((tid & 63) == 0) wmax[wv] = a;
    __syncthreads();
    float m = wmax[0];
#pragma unroll
    for (int r = 1; r < 8; r++) m = fmaxf(m, wmax[r]);

    float ev = 0.0f;
    if (tid <= t) {
        ev = __expf(sc[tid] - m);
        sc[tid] = ev;
    }
    float ssum = ev;
#pragma unroll
    for (int off = 32; off > 0; off >>= 1) ssum += __shfl_xor(ssum, off);
    if ((tid & 63) == 0) wsum[wv] = ssum;
    __syncthreads();
    float tot = wsum[0];
#pragma unroll
    for (int r = 1; r < 8; r++) tot += wsum[r];
    float inv = 1.0f / tot;

    // --- ctx: i-slice = tid>>5 (16 slices), float4 column = tid&31 ---
    int hq = tid & 31;
    int is = tid >> 5;
    float4 acc = {0.0f, 0.0f, 0.0f, 0.0f};
    const float4* ob4 = (const float4*)(out + b * Sn * Hn);
    for (int i = is; i <= t; i += 16) {
        float s = sc[i];
        float4 o4 = ob4[i * (Hn / 4) + hq];
        acc.x += s * o4.x; acc.y += s * o4.y;
        acc.z += s * o4.z; acc.w += s * o4.w;
    }
    ((float4*)part[is])[hq] = acc;
    __syncthreads();
    if (tid < Hn) {
        float sum2 = 0.0f;
#pragma unroll
        for (int r = 0; r < 16; r++) sum2 += part[r][tid];
        oc[Hn + tid] = sum2 * inv;     // ctx stays in LDS
    }
    __syncthreads();

    // --- logits = bf + Wf @ [out_t | ctx_t]: thread (v = tid&127, kq) ---
    {
        int v = tid & 127, kq = tid >> 7;
        const float4* wr = (const float4*)(Wf + v * 2 * Hn + kq * 64);
        const float* ob = oc + kq * 64;
        float a2 = 0.0f;
#pragma unroll
        for (int i = 0; i < 16; i++) {
            float4 w4 = wr[i];
            a2 += w4.x * ob[4*i] + w4.y * ob[4*i+1] + w4.z * ob[4*i+2] + w4.w * ob[4*i+3];
        }
        part[kq][v] = a2;
    }
    __syncthreads();
    if (tid < Hn)
        logits[(b * Sn + t) * Vn + tid] =
            bf[tid] + part[0][tid] + part[1][tid] + part[2][tid] + part[3][tid];
}

extern "C" void kernel_launch(void* const* d_in, const int* in_sizes, int n_in,
                              void* d_out, int out_size, void* d_ws, size_t ws_size,
                              hipStream_t stream) {
    const int*   x   = (const int*)d_in[0];
    const float* emb = (const float*)d_in[1];
    const float* Wih = (const float*)d_in[2];
    const float* Whh = (const float*)d_in[3];
    const float* bih = (const float*)d_in[4];
    const float* bhh = (const float*)d_in[5];
    const float* Wq  = (const float*)d_in[6];
    const float* bq  = (const float*)d_in[7];
    const float* Wk  = (const float*)d_in[8];
    const float* bk  = (const float*)d_in[9];
    const float* v   = (const float*)d_in[10];
    const float* Wf  = (const float*)d_in[11];
    const float* bf  = (const float*)d_in[12];

    float* logits = (float*)d_out;                 // (B,S,V) = 262144
    float* hT     = logits + Bn * Sn * Vn;         // (B,H)   = 512
    float* cT     = hT + Bn * Hn;                  // (B,H)   = 512

    float* ws   = (float*)d_ws;
    float* Gtab = ws;                               // V*4H   = 65536 floats
    float* outb = ws + 65536;                       // B*S*H  = 262144
    float* ko   = ws + 65536 + 262144;

    k_gtab<<<Vn, 512, 0, stream>>>(emb, Wih, bih, bhh, Gtab);
    k_lstm<<<1, 512, 0, stream>>>(Whh, Gtab, x, outb, hT, cT);
    k_k<<<Bn * Sn, 128, 0, stream>>>(outb, Wk, bk, ko);
    k_attn<<<Bn * Sn, 512, 0, stream>>>(ko, v, outb, Wq, bq, Wf, bf, logits);
}